// Round 1
// baseline (3165.015 us; speedup 1.0000x reference)
//
#include <hip/hip_runtime.h>

// ---------------------------------------------------------------------------
// TGN forward, MI355X bf16-MFMA pipeline.
//
// Key algebraic restructurings vs reference (all exact up to fp rounding):
//  * Part-1 (msg MLP + GRU) computed only for msg_mask>0 nodes (compacted
//    list); consumers select memupd vs memory by mask at gather time.
//  * t0 = cos(0*w+b) = cos(b) constant  ->  bq_eff = bq + Wq[:,172:]@cos(b).
//  * k/v projections never materialized: K=20 << 344 so
//      scores[i,h,kk] = (q[i,h] @ Wk_h) . k_in[i,kk]   (kq GEMM, tiny)
//      ctx[i,h]       = Wv_h @ (sum_kk attn*k_in)      (ctx GEMM, tiny)
//    bk shifts all scores of a row equally -> cancels in softmax -> dropped.
//    bv added in ctx epilogue (sum attn == 1 always, incl. all-invalid).
//  * GRU fused into gates-GEMM epilogue. Gate-blocked weight layout
//    [r(176)|z(176)|gi_n(176)|gh_n(176)] x [msg(128)|mem(192)] so that
//    r,z use combined W_ih/W_hh accumulators, n keeps gi/gh separate.
//
// ws layout (bytes), total required ~345.9 MB:
//   relu1/msg (part-1 intermediates) alias with the post-part-1 buffers.
// ---------------------------------------------------------------------------

typedef float fx4 __attribute__((ext_vector_type(4)));
typedef short sx8 __attribute__((ext_vector_type(8)));

#define NNODES 200000
#define N3B    12288

// ---- weight-region element offsets (bf16) ----
#define W_M1  0         // [384][704]
#define W_M2  270336    // [128][352]
#define W_GRU 315392    // [704][320]
#define W_QR  540672    // [384][192]
#define W_KQ  614400    // [2][576][192]
#define W_VS  835584    // [2][192][544]
#define W_OR  1044480   // [384][384]
#define W_G1  1191936   // [192][544]
#define W_G2  1296384   // [192][192]
#define W_TOT 1333248

// ---- bias-region float offsets ----
#define B_M1  0      // 384
#define B_M2  384    // 128
#define B_GRU 512    // 704
#define B_QE  1216   // 384
#define B_VP  1600   // 384
#define B_OP  1984   // 384
#define B_G1  2368   // 192
#define B_G2  2560   // 192
#define B_TOT 2752

// ---- ws byte offsets ----
#define OFF_CNT 0
#define OFF_INV 256
#define OFF_W   12800
#define OFF_B   2679296
#define OFF_ACT 2690304
#define OFF_MU  3490304
#define OFF_R   141090304ull
#define OFF_RELU1 (OFF_R)                    // 200000*384*2 = 153600000
#define OFF_MSG   (OFF_R + 153600000ull)     // 200000*128*2 = 51200000
// post-part-1 aliases (inside relu1's dead space):
#define OFF_SF    (OFF_R)                    // 12288*192*2
#define OFF_QB    (OFF_R + 4718592ull)       // 12288*384*2
#define OFF_KQ    (OFF_R + 14155776ull)      // 12288*1152*2
#define OFF_CTXIN (OFF_R + 42467328ull)      // 12288*1088*4
#define OFF_CTXB  (OFF_R + 95944704ull)      // 12288*384*2
#define OFF_AO    (OFF_R + 105381888ull)     // 12288*384*2
#define OFF_H1    (OFF_R + 114819072ull)     // 12288*192*2

__device__ __forceinline__ unsigned short f2bf_u(float f) {
  unsigned u = __float_as_uint(f);
  u += 0x7FFFu + ((u >> 16) & 1u);
  return (unsigned short)(u >> 16);
}
__device__ __forceinline__ float bf2f(unsigned short u) {
  return __uint_as_float(((unsigned)u) << 16);
}
__device__ __forceinline__ sx8 ld8(const unsigned short* p) { return *(const sx8*)p; }

__device__ __forceinline__ sx8 cvt8(const float* __restrict__ p, int k0, int limit) {
  union { sx8 v; unsigned short u[8]; } r;
  if (k0 + 8 <= limit) {
    fx4 a = *(const fx4*)(p + k0);
    fx4 b = *(const fx4*)(p + k0 + 4);
    r.u[0] = f2bf_u(a[0]); r.u[1] = f2bf_u(a[1]); r.u[2] = f2bf_u(a[2]); r.u[3] = f2bf_u(a[3]);
    r.u[4] = f2bf_u(b[0]); r.u[5] = f2bf_u(b[1]); r.u[6] = f2bf_u(b[2]); r.u[7] = f2bf_u(b[3]);
  } else {
#pragma unroll
    for (int j = 0; j < 8; ++j) {
      int k = k0 + j;
      r.u[j] = f2bf_u(k < limit ? p[k] : 0.f);
    }
  }
  return r.v;
}

__device__ __forceinline__ fx4 mfma16(sx8 a, sx8 b, fx4 c) {
  return __builtin_amdgcn_mfma_f32_16x16x32_bf16(a, b, c, 0, 0, 0);
}

// Core: one wave computes 16 rows x NT col-tiles. A via lambda (8 bf16 at k0),
// B stored as [Npad rows][KPAD] bf16 row-major (i.e. W[n][k]).
template <int KPAD, int NT, class AL>
__device__ __forceinline__ void mma_tiles(AL&& al, const unsigned short* __restrict__ Bb,
                                          int ldb, int col0, int m, int quad, fx4 (&acc)[NT]) {
  const unsigned short* Bl = Bb + (size_t)(col0 + m) * ldb + quad * 8;
  for (int kb = 0; kb < KPAD; kb += 32) {
    sx8 a = al(kb + quad * 8);
#pragma unroll
    for (int t = 0; t < NT; ++t) {
      sx8 b = *(const sx8*)(Bl + (size_t)(t * 16) * ldb + kb);
      acc[t] = mfma16(a, b, acc[t]);
    }
  }
}

// ---------------------------------------------------------------------------
// prep kernels
// ---------------------------------------------------------------------------
__global__ __launch_bounds__(256) void k_prep_w(
    const float* __restrict__ Wm1, const float* __restrict__ Wm2,
    const float* __restrict__ Wih, const float* __restrict__ Whh,
    const float* __restrict__ Wq, const float* __restrict__ Wk,
    const float* __restrict__ Wv, const float* __restrict__ Wo,
    const float* __restrict__ Wg1, const float* __restrict__ Wg2,
    unsigned short* __restrict__ out) {
  int idx = blockIdx.x * 256 + threadIdx.x;
  if (idx >= W_TOT) return;
  int i = idx;
  float val = 0.f;
  if (i < W_M2) {                       // Wm1b [384][704]
    int n = i / 704, k = i - n * 704;
    if (n < 344 && k < 688) val = Wm1[n * 688 + k];
  } else if (i < W_GRU) {               // Wm2b [128][352]
    i -= W_M2;
    int n = i / 352, k = i - n * 352;
    if (n < 100 && k < 344) val = Wm2[n * 344 + k];
  } else if (i < W_QR) {                // Wgru [704][320]
    i -= W_GRU;
    int c = i / 320, k = i - c * 320;
    int g = c / 176, j = c - g * 176;
    if (j < 172) {
      if (k < 128) {
        if (k < 100) {
          int row = (g == 0) ? j : (g == 1) ? 172 + j : (g == 2) ? 344 + j : -1;
          if (row >= 0) val = Wih[row * 100 + k];
        }
      } else {
        int km = k - 128;
        if (km < 172) {
          int row = (g == 0) ? j : (g == 1) ? 172 + j : (g == 3) ? 344 + j : -1;
          if (row >= 0) val = Whh[row * 172 + km];
        }
      }
    }
  } else if (i < W_KQ) {                // Wqr [384][192], out col n'=h*192+d
    i -= W_QR;
    int n = i / 192, k = i - n * 192;
    int h = n / 192 ? 1 : 0; h = n >> 7 >= 1 ? n / 192 : n / 192; // n<384
    h = n / 192; int d = n - h * 192;
    if (d < 172 && k < 172) val = Wq[(h * 172 + d) * 344 + k];
  } else if (i < W_VS) {                // Wkq [2][576][192] : Wk[h*172+d][c] at [h][c][d]
    i -= W_KQ;
    int z = i / (576 * 192); int r2 = i - z * 576 * 192;
    int c = r2 / 192, d = r2 - c * 192;
    if (c < 516 && d < 172) val = Wk[(z * 172 + d) * 516 + c];
  } else if (i < W_OR) {                // Wvs [2][192][544] : Wv[h*172+d][c]
    i -= W_VS;
    int z = i / (192 * 544); int r2 = i - z * 192 * 544;
    int d = r2 / 544, c = r2 - d * 544;
    if (d < 172 && c < 516) val = Wv[(z * 172 + d) * 516 + c];
  } else if (i < W_G1) {                // Wor [384][384], k' = z*192+dd
    i -= W_OR;
    int n = i / 384, kp = i - n * 384;
    int z = kp / 192, dd = kp - z * 192;
    if (n < 344 && dd < 172) val = Wo[n * 344 + z * 172 + dd];
  } else if (i < W_G2) {                // Wg1b [192][544]
    i -= W_G1;
    int n = i / 544, k = i - n * 544;
    if (n < 172 && k < 516) val = Wg1[n * 516 + k];
  } else {                              // Wg2b [192][192]
    i -= W_G2;
    int n = i / 192, k = i - n * 192;
    if (n < 172 && k < 172) val = Wg2[n * 172 + k];
  }
  out[idx] = f2bf_u(val);
}

__global__ __launch_bounds__(256) void k_prep_b(
    const float* __restrict__ bm1, const float* __restrict__ bm2,
    const float* __restrict__ bih, const float* __restrict__ bhh,
    const float* __restrict__ bq, const float* __restrict__ bv,
    const float* __restrict__ bo, const float* __restrict__ bg1,
    const float* __restrict__ bg2, const float* __restrict__ Wq,
    const float* __restrict__ time_b, float* __restrict__ out) {
  int idx = blockIdx.x * 256 + threadIdx.x;
  if (idx >= B_TOT) return;
  int i = idx;
  float val = 0.f;
  if (i < B_M2) {                  // bm1p
    if (i < 344) val = bm1[i];
  } else if (i < B_GRU) {          // bm2p
    i -= B_M2; if (i < 100) val = bm2[i];
  } else if (i < B_QE) {           // bgru [4][176]
    i -= B_GRU;
    int g = i / 176, j = i - g * 176;
    if (j < 172) {
      if (g == 0) val = bih[j] + bhh[j];
      else if (g == 1) val = bih[172 + j] + bhh[172 + j];
      else if (g == 2) val = bih[344 + j];
      else val = bhh[344 + j];
    }
  } else if (i < B_VP) {           // bq_eff [384] (n'=h*192+d)
    i -= B_QE;
    int h = i / 192, d = i - h * 192;
    if (d < 172) {
      float s = bq[h * 172 + d];
      const float* wr = Wq + (size_t)(h * 172 + d) * 344 + 172;
      for (int j = 0; j < 172; ++j) s += wr[j] * cosf(time_b[j]);
      val = s;
    }
  } else if (i < B_OP) {           // bvp [384]
    i -= B_VP;
    int z = i / 192, d = i - z * 192;
    if (d < 172) val = bv[z * 172 + d];
  } else if (i < B_G1) {           // bop
    i -= B_OP; if (i < 344) val = bo[i];
  } else if (i < B_G2) {           // bg1p
    i -= B_G1; if (i < 172) val = bg1[i];
  } else {                         // bg2p
    i -= B_G2; if (i < 172) val = bg2[i];
  }
  out[idx] = val;
}

__global__ __launch_bounds__(256) void k_act(const int* __restrict__ mask,
                                             int* __restrict__ cnt, int* __restrict__ act) {
  int i = blockIdx.x * 256 + threadIdx.x;
  if (i < NNODES && mask[i] > 0) act[atomicAdd(cnt, 1)] = i;
}

// ---------------------------------------------------------------------------
// Part 1: relu1 = relu(raw[act] @ Wm1.T + bm1)       [Mact][384] bf16
// ---------------------------------------------------------------------------
__global__ __launch_bounds__(256) void k_g1(const float* __restrict__ raw,
    const int* __restrict__ act, const int* __restrict__ cnt,
    const unsigned short* __restrict__ Bw, const float* __restrict__ bias,
    unsigned short* __restrict__ out) {
  const int M = *cnt;
  const int row0b = blockIdx.y * 64;
  if (row0b >= M) return;
  const int tid = threadIdx.x, w = tid >> 6, lane = tid & 63, m = lane & 15, quad = lane >> 4;
  const int row0 = row0b + w * 16;
  int ar = row0 + m; if (ar >= M) ar = M - 1;
  const float* Ar = raw + (size_t)act[ar] * 688;
  const int col0 = blockIdx.x * 192;
  fx4 acc[12];
#pragma unroll
  for (int t = 0; t < 12; ++t) acc[t] = (fx4){0.f, 0.f, 0.f, 0.f};
  mma_tiles<704, 12>([&](int k0) { return cvt8(Ar, k0, 688); }, Bw, 704, col0, m, quad, acc);
#pragma unroll
  for (int t = 0; t < 12; ++t) {
    int col = col0 + t * 16 + m;
    float bv = bias[col];
#pragma unroll
    for (int r = 0; r < 4; ++r) {
      int row = row0 + quad * 4 + r;
      if (row < M) out[(size_t)row * 384 + col] = f2bf_u(fmaxf(acc[t][r] + bv, 0.f));
    }
  }
}

// msg = relu1 @ Wm2.T + bm2     [Mact][128] bf16
__global__ __launch_bounds__(256) void k_g2(const unsigned short* __restrict__ relu1,
    const int* __restrict__ cnt, const unsigned short* __restrict__ Bw,
    const float* __restrict__ bias, unsigned short* __restrict__ out) {
  const int M = *cnt;
  const int row0b = blockIdx.y * 64;
  if (row0b >= M) return;
  const int tid = threadIdx.x, w = tid >> 6, lane = tid & 63, m = lane & 15, quad = lane >> 4;
  const int row0 = row0b + w * 16;
  int ar = row0 + m; if (ar >= M) ar = M - 1;
  const unsigned short* Ar = relu1 + (size_t)ar * 384;
  fx4 acc[8];
#pragma unroll
  for (int t = 0; t < 8; ++t) acc[t] = (fx4){0.f, 0.f, 0.f, 0.f};
  mma_tiles<352, 8>([&](int k0) { return ld8(Ar + k0); }, Bw, 352, 0, m, quad, acc);
#pragma unroll
  for (int t = 0; t < 8; ++t) {
    int col = t * 16 + m;
    float bv = bias[col];
#pragma unroll
    for (int r = 0; r < 4; ++r) {
      int row = row0 + quad * 4 + r;
      if (row < M) out[(size_t)row * 128 + col] = f2bf_u(acc[t][r] + bv);
    }
  }
}

// gates GEMM + fused GRU epilogue -> memupd[node] rows (masked nodes only)
__global__ __launch_bounds__(256) void k_gru(const unsigned short* __restrict__ msg,
    const float* __restrict__ memory, const int* __restrict__ act, const int* __restrict__ cnt,
    const unsigned short* __restrict__ Wg, const float* __restrict__ bg,
    float* __restrict__ memupd) {
  const int M = *cnt;
  const int row0 = blockIdx.y * 16;
  if (row0 >= M) return;
  const int tid = threadIdx.x, w = tid >> 6, lane = tid & 63, m = lane & 15, quad = lane >> 4;
  const int jt = w * 3 + blockIdx.x;     // 0..11, 11 dropped
  if (jt >= 11) return;
  int ar = row0 + m; if (ar >= M) ar = M - 1;
  const unsigned short* Am = msg + (size_t)ar * 128;
  const float* Ah = memory + (size_t)act[ar] * 172;
  fx4 acc[4];
#pragma unroll
  for (int g = 0; g < 4; ++g) acc[g] = (fx4){0.f, 0.f, 0.f, 0.f};
  const unsigned short* B0 = Wg + (size_t)(jt * 16 + m) * 320 + quad * 8;
  for (int kb = 0; kb < 128; kb += 32) {
    sx8 a = ld8(Am + kb + quad * 8);
#pragma unroll
    for (int g = 0; g < 4; ++g) {
      sx8 b = *(const sx8*)(B0 + (size_t)g * 176 * 320 + kb);
      acc[g] = mfma16(a, b, acc[g]);
    }
  }
  for (int kb = 128; kb < 320; kb += 32) {
    sx8 a = cvt8(Ah, kb - 128 + quad * 8, 172);
#pragma unroll
    for (int g = 0; g < 4; ++g) {
      sx8 b = *(const sx8*)(B0 + (size_t)g * 176 * 320 + kb);
      acc[g] = mfma16(a, b, acc[g]);
    }
  }
  int j = jt * 16 + m;
  if (j < 172) {
    float br = bg[j], bz = bg[176 + j], bi = bg[352 + j], bh = bg[528 + j];
#pragma unroll
    for (int r = 0; r < 4; ++r) {
      int row = row0 + quad * 4 + r;
      if (row < M) {
        int node = act[row];
        float mem = memory[(size_t)node * 172 + j];
        float rr = 1.f / (1.f + __expf(-(acc[0][r] + br)));
        float zz = 1.f / (1.f + __expf(-(acc[1][r] + bz)));
        float nn = tanhf(acc[2][r] + bi + rr * (acc[3][r] + bh));
        memupd[(size_t)node * 172 + j] = (1.f - zz) * nn + zz * mem;
      }
    }
  }
}

// ---------------------------------------------------------------------------
// src_feat (bf16, padded to 192): (mask? memupd: memory)[node] + node_feats
// ---------------------------------------------------------------------------
__global__ __launch_bounds__(256) void k_sfeat(const int* __restrict__ src,
    const int* __restrict__ dst, const int* __restrict__ neg, const int* __restrict__ mask,
    const float* __restrict__ memupd, const float* __restrict__ memory,
    const float* __restrict__ nfeat, unsigned short* __restrict__ sfeat) {
  int idx = blockIdx.x * 256 + threadIdx.x;   // 12288*192 exact
  int row = idx / 192, col = idx - row * 192;
  int node = (row < 4096) ? src[row] : (row < 8192) ? dst[row - 4096] : neg[row - 8192];
  float v = 0.f;
  if (col < 172) {
    const float* tbl = (mask[node] > 0) ? memupd : memory;
    v = tbl[(size_t)node * 172 + col] + nfeat[(size_t)node * 172 + col];
  }
  sfeat[idx] = f2bf_u(v);
}

// q = sfeat @ Wq_f.T + bq_eff   -> qbf [12288][384] (cols = h*192+d)
__global__ __launch_bounds__(256) void k_q(const unsigned short* __restrict__ sfeat,
    const unsigned short* __restrict__ Bw, const float* __restrict__ bias,
    unsigned short* __restrict__ out) {
  const int tid = threadIdx.x, w = tid >> 6, lane = tid & 63, m = lane & 15, quad = lane >> 4;
  const int row0 = blockIdx.y * 64 + w * 16;
  const unsigned short* Ar = sfeat + (size_t)(row0 + m) * 192;
  const int col0 = blockIdx.x * 128;
  fx4 acc[8];
#pragma unroll
  for (int t = 0; t < 8; ++t) acc[t] = (fx4){0.f, 0.f, 0.f, 0.f};
  mma_tiles<192, 8>([&](int k0) { return ld8(Ar + k0); }, Bw, 192, col0, m, quad, acc);
#pragma unroll
  for (int t = 0; t < 8; ++t) {
    int col = col0 + t * 16 + m;
    float bv = bias[col];
#pragma unroll
    for (int r = 0; r < 4; ++r)
      out[(size_t)(row0 + quad * 4 + r) * 384 + col] = f2bf_u(acc[t][r] + bv);
  }
}

// kq[i,h,c] = sum_d q[i,h,d] * Wk[h*172+d][c]  -> kqbf [12288][2*576]
__global__ __launch_bounds__(256) void k_kq(const unsigned short* __restrict__ qbf,
    const unsigned short* __restrict__ Bw, unsigned short* __restrict__ out) {
  const int z = blockIdx.z;
  const int tid = threadIdx.x, w = tid >> 6, lane = tid & 63, m = lane & 15, quad = lane >> 4;
  const int row0 = blockIdx.y * 64 + w * 16;
  const unsigned short* Ar = qbf + (size_t)(row0 + m) * 384 + z * 192;
  const int col0 = blockIdx.x * 96;
  fx4 acc[6];
#pragma unroll
  for (int t = 0; t < 6; ++t) acc[t] = (fx4){0.f, 0.f, 0.f, 0.f};
  mma_tiles<192, 6>([&](int k0) { return ld8(Ar + k0); }, Bw + (size_t)z * 576 * 192, 192,
                    col0, m, quad, acc);
#pragma unroll
  for (int t = 0; t < 6; ++t) {
    int col = col0 + t * 16 + m;
#pragma unroll
    for (int r = 0; r < 4; ++r)
      out[(size_t)(row0 + quad * 4 + r) * 1152 + z * 576 + col] = f2bf_u(acc[t][r]);
  }
}

// ---------------------------------------------------------------------------
// attention: build k_in in LDS, scores = kq . k_in, softmax, ctxin = attn-wsum
// ---------------------------------------------------------------------------
__global__ __launch_bounds__(256) void k_attn(const int* __restrict__ nbr,
    const int* __restrict__ eidx, const float* __restrict__ etime,
    const float* __restrict__ ntime, const int* __restrict__ mask,
    const float* __restrict__ memupd, const float* __restrict__ memory,
    const float* __restrict__ nfeat, const float* __restrict__ efeat,
    const float* __restrict__ tw, const float* __restrict__ tb,
    const unsigned short* __restrict__ kq, float* __restrict__ ctxin,
    unsigned char* __restrict__ allinv) {
  __shared__ float kin[20 * 528];
  __shared__ float sc[40];
  __shared__ float aw[40];
  const int i = blockIdx.x;
  const int tid = threadIdx.x;
  const float tsv = etime[i & 4095];
  for (int idx = tid; idx < 20 * 528; idx += 256) {
    int kk = idx / 528, c = idx - kk * 528;
    float v = 0.f;
    int nb = nbr[i * 20 + kk];
    if (c < 172) {
      const float* tbl = (mask[nb] > 0) ? memupd : memory;
      v = tbl[(size_t)nb * 172 + c] + nfeat[(size_t)nb * 172 + c];
    } else if (c < 344) {
      v = efeat[(size_t)eidx[i * 20 + kk] * 172 + (c - 172)];
    } else if (c < 516) {
      int j = c - 344;
      float dt = tsv - ntime[i * 20 + kk];
      v = __cosf(dt * tw[j] + tb[j]);
    }
    kin[idx] = v;
  }
  __syncthreads();
  const int w = tid >> 6, lane = tid & 63;
  for (int p = w; p < 40; p += 4) {
    int h = p / 20, kk = p - h * 20;
    const unsigned short* kqr = kq + (size_t)i * 1152 + h * 576;
    const float* kr = kin + kk * 528;
    float s = 0.f;
    for (int c = lane; c < 516; c += 64) s += bf2f(kqr[c]) * kr[c];
#pragma unroll
    for (int off = 32; off > 0; off >>= 1) s += __shfl_down(s, off);
    if (lane == 0) {
      bool valid = nbr[i * 20 + kk] > 0;
      sc[p] = valid ? s * 0.0762492852f : -1e9f;   // 1/sqrt(172)
    }
  }
  __syncthreads();
  if (w < 2) {
    float sv = (lane < 20) ? sc[w * 20 + lane] : -1e30f;
    float mx = sv;
#pragma unroll
    for (int off = 32; off > 0; off >>= 1) mx = fmaxf(mx, __shfl_xor(mx, off));
    float e = (lane < 20) ? __expf(sv - mx) : 0.f;
    float sum = e;
#pragma unroll
    for (int off = 32; off > 0; off >>= 1) sum += __shfl_xor(sum, off);
    if (lane < 20) aw[w * 20 + lane] = e / sum;
  } else if (w == 2) {
    bool v = (lane < 20) && (nbr[i * 20 + lane] > 0);
    unsigned long long b = __ballot(v);
    if (lane == 0) allinv[i] = (b == 0ull) ? 1 : 0;
  }
  __syncthreads();
  for (int idx = tid; idx < 2 * 544; idx += 256) {
    int h = idx / 544, c = idx - h * 544;
    float s = 0.f;
    if (c < 528) {
      const float* kc = kin + c;
#pragma unroll
      for (int kk = 0; kk < 20; ++kk) s += aw[h * 20 + kk] * kc[kk * 528];
    }
    ctxin[(size_t)i * 1088 + idx] = s;
  }
}

// ctx = ctxin_h @ Wv_h.T + bv_h   -> ctxbf [12288][384] (cols h*192+d)
__global__ __launch_bounds__(256) void k_ctx(const float* __restrict__ ctxin,
    const unsigned short* __restrict__ Bw, const float* __restrict__ bias,
    unsigned short* __restrict__ out) {
  const int z = blockIdx.z;
  const int tid = threadIdx.x, w = tid >> 6, lane = tid & 63, m = lane & 15, quad = lane >> 4;
  const int row0 = blockIdx.y * 64 + w * 16;
  const float* Ar = ctxin + (size_t)(row0 + m) * 1088 + z * 544;
  const int col0 = blockIdx.x * 64;
  fx4 acc[4];
#pragma unroll
  for (int t = 0; t < 4; ++t) acc[t] = (fx4){0.f, 0.f, 0.f, 0.f};
  mma_tiles<544, 4>([&](int k0) { return cvt8(Ar, k0, 544); }, Bw + (size_t)z * 192 * 544, 544,
                    col0, m, quad, acc);
#pragma unroll
  for (int t = 0; t < 4; ++t) {
    int col = col0 + t * 16 + m;
    float bv = bias[z * 192 + col];
#pragma unroll
    for (int r = 0; r < 4; ++r)
      out[(size_t)(row0 + quad * 4 + r) * 384 + z * 192 + col] = f2bf_u(acc[t][r] + bv);
  }
}

// attn_out = ctx @ Wo.T + bo, zeroed where all-invalid  -> [12288][384] bf16
__global__ __launch_bounds__(256) void k_wo(const unsigned short* __restrict__ ctxbf,
    const unsigned short* __restrict__ Bw, const float* __restrict__ bias,
    const unsigned char* __restrict__ allinv, unsigned short* __restrict__ out) {
  const int tid = threadIdx.x, w = tid >> 6, lane = tid & 63, m = lane & 15, quad = lane >> 4;
  const int row0 = blockIdx.y * 64 + w * 16;
  const unsigned short* Ar = ctxbf + (size_t)(row0 + m) * 384;
  const int col0 = blockIdx.x * 128;
  fx4 acc[8];
#pragma unroll
  for (int t = 0; t < 8; ++t) acc[t] = (fx4){0.f, 0.f, 0.f, 0.f};
  mma_tiles<384, 8>([&](int k0) { return ld8(Ar + k0); }, Bw, 384, col0, m, quad, acc);
#pragma unroll
  for (int t = 0; t < 8; ++t) {
    int col = col0 + t * 16 + m;
    float bv = bias[col];
#pragma unroll
    for (int r = 0; r < 4; ++r) {
      int row = row0 + quad * 4 + r;
      float v = allinv[row] ? 0.f : acc[t][r] + bv;
      out[(size_t)row * 384 + col] = f2bf_u(v);
    }
  }
}

// h1 = relu([attn_out | src_feat] @ Wg1.T + bg1)  -> [12288][192] bf16
__global__ __launch_bounds__(256) void k_m1(const unsigned short* __restrict__ ao,
    const unsigned short* __restrict__ sfeat, const unsigned short* __restrict__ Bw,
    const float* __restrict__ bias, unsigned short* __restrict__ out) {
  const int tid = threadIdx.x, w = tid >> 6, lane = tid & 63, m = lane & 15, quad = lane >> 4;
  const int row0 = blockIdx.y * 64 + w * 16;
  const unsigned short* Aa = ao + (size_t)(row0 + m) * 384;
  const unsigned short* As = sfeat + (size_t)(row0 + m) * 192;
  const int col0 = blockIdx.x * 64;
  fx4 acc[4];
#pragma unroll
  for (int t = 0; t < 4; ++t) acc[t] = (fx4){0.f, 0.f, 0.f, 0.f};
  mma_tiles<544, 4>([&](int k0) { return (k0 < 344) ? ld8(Aa + k0) : ld8(As + (k0 - 344)); },
                    Bw, 544, col0, m, quad, acc);
#pragma unroll
  for (int t = 0; t < 4; ++t) {
    int col = col0 + t * 16 + m;
    float bv = bias[col];
#pragma unroll
    for (int r = 0; r < 4; ++r)
      out[(size_t)(row0 + quad * 4 + r) * 192 + col] = f2bf_u(fmaxf(acc[t][r] + bv, 0.f));
  }
}

// emb = h1 @ Wg2.T + bg2 -> d_out fp32 [12288][172]
__global__ __launch_bounds__(256) void k_m2(const unsigned short* __restrict__ h1,
    const unsigned short* __restrict__ Bw, const float* __restrict__ bias,
    float* __restrict__ out) {
  const int tid = threadIdx.x, w = tid >> 6, lane = tid & 63, m = lane & 15, quad = lane >> 4;
  const int row0 = blockIdx.y * 64 + w * 16;
  const unsigned short* Ar = h1 + (size_t)(row0 + m) * 192;
  const int col0 = blockIdx.x * 64;
  fx4 acc[4];
#pragma unroll
  for (int t = 0; t < 4; ++t) acc[t] = (fx4){0.f, 0.f, 0.f, 0.f};
  mma_tiles<192, 4>([&](int k0) { return ld8(Ar + k0); }, Bw, 192, col0, m, quad, acc);
#pragma unroll
  for (int t = 0; t < 4; ++t) {
    int col = col0 + t * 16 + m;
    if (col < 172) {
      float bv = bias[col];
#pragma unroll
      for (int r = 0; r < 4; ++r)
        out[(size_t)(row0 + quad * 4 + r) * 172 + col] = acc[t][r] + bv;
    }
  }
}

// ---------------------------------------------------------------------------
extern "C" void kernel_launch(void* const* d_in, const int* in_sizes, int n_in,
                              void* d_out, int out_size, void* d_ws, size_t ws_size,
                              hipStream_t stream) {
  const int* src = (const int*)d_in[0];
  const int* dst = (const int*)d_in[1];
  const int* neg = (const int*)d_in[2];
  const int* nbr = (const int*)d_in[3];
  const int* nbr_eidx = (const int*)d_in[4];
  const int* msg_mask = (const int*)d_in[5];
  const float* edge_times = (const float*)d_in[6];
  const float* nbr_times = (const float*)d_in[7];
  const float* memory = (const float*)d_in[8];
  const float* node_feats = (const float*)d_in[9];
  const float* edge_feats = (const float*)d_in[10];
  const float* raw_msgs = (const float*)d_in[11];
  const float* time_w = (const float*)d_in[12];
  const float* time_b = (const float*)d_in[13];
  const float* Wm1 = (const float*)d_in[14];
  const float* bm1 = (const float*)d_in[15];
  const float* Wm2 = (const float*)d_in[16];
  const float* bm2 = (const float*)d_in[17];
  const float* Wih = (const float*)d_in[18];
  const float* bih = (const float*)d_in[19];
  const float* Whh = (const float*)d_in[20];
  const float* bhh = (const float*)d_in[21];
  const float* Wq = (const float*)d_in[22];
  const float* bq = (const float*)d_in[23];
  const float* Wk = (const float*)d_in[24];
  // d_in[25] = bk: shifts all scores of a row equally -> cancels in softmax.
  const float* Wv = (const float*)d_in[26];
  const float* bv = (const float*)d_in[27];
  const float* Wo = (const float*)d_in[28];
  const float* bo = (const float*)d_in[29];
  const float* Wg1 = (const float*)d_in[30];
  const float* bg1 = (const float*)d_in[31];
  const float* Wg2 = (const float*)d_in[32];
  const float* bg2 = (const float*)d_in[33];

  char* W = (char*)d_ws;
  int* cnt = (int*)(W + OFF_CNT);
  unsigned char* allinv = (unsigned char*)(W + OFF_INV);
  unsigned short* wreg = (unsigned short*)(W + OFF_W);
  unsigned short* Wm1b = wreg + W_M1;
  unsigned short* Wm2b = wreg + W_M2;
  unsigned short* Wgru = wreg + W_GRU;
  unsigned short* Wqr = wreg + W_QR;
  unsigned short* Wkq = wreg + W_KQ;
  unsigned short* Wvs = wreg + W_VS;
  unsigned short* Wor = wreg + W_OR;
  unsigned short* Wg1b = wreg + W_G1;
  unsigned short* Wg2b = wreg + W_G2;
  float* breg = (float*)(W + OFF_B);
  int* act = (int*)(W + OFF_ACT);
  float* memupd = (float*)(W + OFF_MU);
  unsigned short* relu1 = (unsigned short*)(W + OFF_RELU1);
  unsigned short* msg = (unsigned short*)(W + OFF_MSG);
  unsigned short* sfeat = (unsigned short*)(W + OFF_SF);
  unsigned short* qbf = (unsigned short*)(W + OFF_QB);
  unsigned short* kqbf = (unsigned short*)(W + OFF_KQ);
  float* ctxin = (float*)(W + OFF_CTXIN);
  unsigned short* ctxbf = (unsigned short*)(W + OFF_CTXB);
  unsigned short* ao = (unsigned short*)(W + OFF_AO);
  unsigned short* h1 = (unsigned short*)(W + OFF_H1);

  hipMemsetAsync(cnt, 0, 4, stream);
  k_prep_w<<<W_TOT / 256, 256, 0, stream>>>(Wm1, Wm2, Wih, Whh, Wq, Wk, Wv, Wo, Wg1, Wg2, wreg);
  k_prep_b<<<(B_TOT + 255) / 256, 256, 0, stream>>>(bm1, bm2, bih, bhh, bq, bv, bo, bg1, bg2,
                                                    Wq, time_b, breg);
  k_act<<<(NNODES + 255) / 256, 256, 0, stream>>>(msg_mask, cnt, act);
  k_g1<<<dim3(2, 3125), 256, 0, stream>>>(raw_msgs, act, cnt, Wm1b, breg + B_M1, relu1);
  k_g2<<<dim3(1, 3125), 256, 0, stream>>>(relu1, cnt, Wm2b, breg + B_M2, msg);
  k_gru<<<dim3(3, 12500), 256, 0, stream>>>(msg, memory, act, cnt, Wgru, breg + B_GRU, memupd);
  k_sfeat<<<(N3B * 192) / 256, 256, 0, stream>>>(src, dst, neg, msg_mask, memupd, memory,
                                                 node_feats, sfeat);
  k_q<<<dim3(3, 192), 256, 0, stream>>>(sfeat, Wqr, breg + B_QE, qbf);
  k_kq<<<dim3(6, 192, 2), 256, 0, stream>>>(qbf, Wkq, kqbf);
  k_attn<<<N3B, 256, 0, stream>>>(nbr, nbr_eidx, edge_times, nbr_times, msg_mask, memupd,
                                  memory, node_feats, edge_feats, time_w, time_b, kqbf,
                                  ctxin, allinv);
  k_ctx<<<dim3(3, 192, 2), 256, 0, stream>>>(ctxin, Wvs, breg + B_VP, ctxbf);
  k_wo<<<dim3(3, 192), 256, 0, stream>>>(ctxbf, Wor, breg + B_OP, allinv, ao);
  k_m1<<<dim3(3, 192), 256, 0, stream>>>(ao, sfeat, Wg1b, breg + B_G1, h1);
  k_m2<<<dim3(3, 192), 256, 0, stream>>>(h1, Wg2b, breg + B_G2, (float*)d_out);
}